// Round 5
// baseline (526.643 us; speedup 1.0000x reference)
//
#include <hip/hip_runtime.h>
#include <math.h>

#define NNODES 100000
#define NFEAT  256
#define HID    128
#define NCLS   40
#define KHOP   4
#define RWSAMP 10
#define KP1    5

// feature slicing of the fp8 table: [NSLICE][NNODES][SLB bytes]
#define NSLICE 4
#define SLB    32
#define NBAGG  ((NNODES + 7) / 8)

typedef __bf16 bf16;
typedef __attribute__((ext_vector_type(8)))  __bf16 bf16x8;
typedef __attribute__((ext_vector_type(2)))  float  f32x2;
typedef __attribute__((ext_vector_type(16))) float  f32x16;

// ---------------------------------------------------------------------------
// Prep: transpose+convert weights to bf16 [n][k] layout.
// ---------------------------------------------------------------------------
__global__ __launch_bounds__(256) void prep_w(
    const float* __restrict__ W0, const float* __restrict__ W1,
    const float* __restrict__ W2,
    bf16* __restrict__ Wt0, bf16* __restrict__ Wt1, bf16* __restrict__ Wt2)
{
    int tid = blockIdx.x * 256 + threadIdx.x;
    if (tid < 128 * 256) {
        int n = tid >> 8, k = tid & 255;
        Wt0[tid] = (bf16)W0[k * 128 + n];
    } else if (tid < 128 * 256 + 128 * 128) {
        int i = tid - 128 * 256;
        int n = i >> 7, k = i & 127;
        Wt1[i] = (bf16)W1[k * 128 + n];
    } else if (tid < 128 * 256 + 128 * 128 + 64 * 128) {
        int i = tid - (128 * 256 + 128 * 128);
        int n = i >> 7, k = i & 127;
        Wt2[i] = (n < NCLS) ? (bf16)W2[k * NCLS + n] : (bf16)0.0f;
    }
}

// ---------------------------------------------------------------------------
// GEMM: MFMA 32x32x16 bf16; output a SLICE-MAJOR fp8-e4m3 table
// [NSLICE][NNODES][32B] (R11 layout change for per-XCD-L2-resident agg).
// ---------------------------------------------------------------------------
template<int K, bool A_BF16>
__global__ __launch_bounds__(256) void gemm_nodes(
    const void* __restrict__ Av, const bf16* __restrict__ Wt,
    const float* __restrict__ bias, unsigned char* __restrict__ F8, int M)
{
    constexpr int BK  = 128;
    constexpr int LDB = BK + 4;
    __shared__ bf16 Bs[128 * LDB];
    __shared__ bf16 As[4][32 * LDB];

    const int tid  = threadIdx.x;
    const int wv   = tid >> 6;
    const int lane = tid & 63;
    const int l31  = lane & 31;
    const int lhi  = lane >> 5;
    const int blockRow = blockIdx.x * 128;
    const int rowBase  = blockRow + wv * 32;

    const bf16*  Ab = (const bf16*)Av;
    const float* Af = (const float*)Av;

    f32x16 acc[4];
#pragma unroll
    for (int t = 0; t < 4; ++t)
#pragma unroll
        for (int r = 0; r < 16; ++r) acc[t][r] = 0.0f;

    for (int k0 = 0; k0 < K; k0 += BK) {
        if (k0) __syncthreads();
#pragma unroll 4
        for (int l = 0; l < 8; ++l) {
            int c   = tid + l * 256;
            int row = c >> 4;
            int kc  = (c & 15) * 8;
            uint4 v = *(const uint4*)(Wt + (size_t)row * K + k0 + kc);
            *(uint2*)&Bs[row * LDB + kc]     = make_uint2(v.x, v.y);
            *(uint2*)&Bs[row * LDB + kc + 4] = make_uint2(v.z, v.w);
        }
        __syncthreads();

        if (A_BF16) {
#pragma unroll 4
            for (int l = 0; l < 8; ++l) {
                int c  = lane + l * 64;
                int r  = c >> 4;
                int kc = (c & 15) * 8;
                int gr = min(rowBase + r, M - 1);
                uint4 v = *(const uint4*)(Ab + (size_t)gr * K + k0 + kc);
                *(uint2*)&As[wv][r * LDB + kc]     = make_uint2(v.x, v.y);
                *(uint2*)&As[wv][r * LDB + kc + 4] = make_uint2(v.z, v.w);
            }
        } else {
#pragma unroll 4
            for (int l = 0; l < 16; ++l) {
                int c  = lane + l * 64;
                int r  = c >> 5;
                int kc = (c & 31) * 4;
                int gr = min(rowBase + r, M - 1);
                float4 v = *(const float4*)(Af + (size_t)gr * K + k0 + kc);
                union { bf16 h[4]; uint2 u; } t4;
                t4.h[0] = (bf16)v.x; t4.h[1] = (bf16)v.y;
                t4.h[2] = (bf16)v.z; t4.h[3] = (bf16)v.w;
                *(uint2*)&As[wv][r * LDB + kc] = t4.u;
            }
        }

#pragma unroll
        for (int ks = 0; ks < BK / 16; ++ks) {
            const int ko = ks * 16 + lhi * 8;
            union { uint2 u2[2]; bf16x8 v; } ua, ub;
            ua.u2[0] = *(const uint2*)&As[wv][l31 * LDB + ko];
            ua.u2[1] = *(const uint2*)&As[wv][l31 * LDB + ko + 4];
            bf16x8 a = ua.v;
#pragma unroll
            for (int t = 0; t < 4; ++t) {
                ub.u2[0] = *(const uint2*)&Bs[(t * 32 + l31) * LDB + ko];
                ub.u2[1] = *(const uint2*)&Bs[(t * 32 + l31) * LDB + ko + 4];
                acc[t] = __builtin_amdgcn_mfma_f32_32x32x16_bf16(a, ub.v, acc[t], 0, 0, 0);
            }
        }
    }

    __syncthreads();
    unsigned* ldsq = (unsigned*)Bs;   // [32 rowquads][128 cols]

#pragma unroll
    for (int t = 0; t < 4; ++t) {
        int col = t * 32 + l31;
        float bc = bias[col];
#pragma unroll
        for (int G = 0; G < 4; ++G) {
            float v0 = acc[t][4 * G + 0] + bc;
            float v1 = acc[t][4 * G + 1] + bc;
            float v2 = acc[t][4 * G + 2] + bc;
            float v3 = acc[t][4 * G + 3] + bc;
            int p = __builtin_amdgcn_cvt_pk_fp8_f32(v0, v1, 0, false);
            p = __builtin_amdgcn_cvt_pk_fp8_f32(v2, v3, p, true);
            ldsq[(wv * 8 + 2 * G + lhi) * 128 + col] = (unsigned)p;
        }
    }
    __syncthreads();

    {
        const int j  = tid & 31;
        const int Q0 = (tid >> 5) * 4;
        const int slice = j >> 3;          // 8 dwords = 32B per slice
        const int b4    = (j & 7) * 4;     // byte offset within slice row
#pragma unroll
        for (int qq = 0; qq < 4; ++qq) {
            int Q = Q0 + qq;
            uint4 d = *(const uint4*)&ldsq[Q * 128 + 4 * j];
            int growb = blockRow + 4 * Q;
#pragma unroll
            for (int i = 0; i < 4; ++i) {
                unsigned sel = ((unsigned)(4 + i) << 8) | (unsigned)i;
                unsigned lo = __builtin_amdgcn_perm(d.y, d.x, sel);
                unsigned hi = __builtin_amdgcn_perm(d.w, d.z, sel);
                unsigned o  = __builtin_amdgcn_perm(hi, lo, 0x05040100u);
                if (growb + i < M)
                    *(unsigned*)(F8 + ((size_t)slice * NNODES + (growb + i)) * SLB + b4) = o;
            }
        }
    }
}

// ---------------------------------------------------------------------------
// Aggregation + ReLU, slice-partitioned (R11).
// Theory: agg is L2-CAPACITY-bound (R4 falsified latency: 8x MLP made it
// slower; miss path 202MB @ 2.8 TB/s = the whole 72us). Each grid-slice
// works one 3.2MB table slice ([NSLICE][NNODES][32B], slice OUTER-major in
// blockIdx) so all resident blocks touch the same slice -> it lives in
// every XCD's 4MB L2 -> misses collapse to compulsory redistribution.
// Wave = 2 nodes; 16 groups of 4 lanes; group g: walks j=8t+(g&7) of node
// (lane>>5); lane owns 8 features of the 32-feature slice; self = walk 40.
// ---------------------------------------------------------------------------
__global__ __launch_bounds__(256) void agg_relu_fp8(
    const unsigned char* __restrict__ hf8s,   // [NSLICE][NNODES][SLB]
    bf16* __restrict__ hout,
    const int* __restrict__ ends, const float* __restrict__ degree,
    const float* __restrict__ att)
{
    __shared__ int   sewE[4][2][41];   // byte offset within slice (e*32)
    __shared__ float sewW[4][2][41];

    const int slice = blockIdx.x / NBAGG;
    const int nb    = blockIdx.x - slice * NBAGG;
    const int wv    = threadIdx.x >> 6;
    const int lane  = threadIdx.x & 63;
    const int n0    = nb * 8 + wv * 2;       // wave handles n0, n0+1

    for (int en = lane; en < 82; en += 64) {
        int node = en > 40;
        int j = en - node * 41;              // 0..40; 40 = self
        int n = n0 + node;
        int e; float w;
        if (j == 40) {
            e = n;
            w = att[0];
        } else {
            int k = j / RWSAMP, s = j - k * RWSAMP;
            e = ends[(size_t)k * (NNODES * RWSAMP) + (size_t)n * RWSAMP + s];
            w = att[k + 1] * (1.0f / RWSAMP) * sqrtf(degree[n]) * rsqrtf(degree[e]);
        }
        sewE[wv][node][j] = e << 5;          // e * SLB
        sewW[wv][node][j] = w;
    }
    // wave-private LDS region: same-wave producer/consumer, in-order DS pipe

    const int node = lane >> 5;              // 0 or 1
    const int g7   = (lane >> 2) & 7;        // walk subgroup
    const int il   = lane & 3;               // 8B chunk within 32B row
    const unsigned char* sbase =
        hf8s + (size_t)slice * ((size_t)NNODES * SLB) + il * 8;

    f32x2 a[4];
#pragma unroll
    for (int i = 0; i < 4; ++i) a[i] = (f32x2){0.f, 0.f};

#pragma unroll
    for (int t = 0; t < 6; ++t) {
        int j = 8 * t + g7;
        if (j < 41) {
            int   eo = sewE[wv][node][j];
            float w  = sewW[wv][node][j];
            uint2 gch = *(const uint2*)(sbase + (unsigned)eo);
            f32x2 w2 = {w, w};
            a[0] = __builtin_elementwise_fma(w2, __builtin_amdgcn_cvt_pk_f32_fp8((int)gch.x, false), a[0]);
            a[1] = __builtin_elementwise_fma(w2, __builtin_amdgcn_cvt_pk_f32_fp8((int)gch.x, true),  a[1]);
            a[2] = __builtin_elementwise_fma(w2, __builtin_amdgcn_cvt_pk_f32_fp8((int)gch.y, false), a[2]);
            a[3] = __builtin_elementwise_fma(w2, __builtin_amdgcn_cvt_pk_f32_fp8((int)gch.y, true),  a[3]);
        }
    }

    // reduce the 8 walk-subgroups (same node, same il): xor 4, 8, 16
#pragma unroll
    for (int i = 0; i < 4; ++i) {
        a[i].x += __shfl_xor(a[i].x, 4, 64);  a[i].y += __shfl_xor(a[i].y, 4, 64);
        a[i].x += __shfl_xor(a[i].x, 8, 64);  a[i].y += __shfl_xor(a[i].y, 8, 64);
        a[i].x += __shfl_xor(a[i].x, 16, 64); a[i].y += __shfl_xor(a[i].y, 16, 64);
    }

    if (g7 == 0) {
        const int n = n0 + node;
        f32x2 z = {0.f, 0.f};
#pragma unroll
        for (int i = 0; i < 4; ++i) a[i] = __builtin_elementwise_max(a[i], z);

        union { bf16 h[8]; uint4 u; } st;
        st.h[0] = (bf16)a[0].x; st.h[1] = (bf16)a[0].y;
        st.h[2] = (bf16)a[1].x; st.h[3] = (bf16)a[1].y;
        st.h[4] = (bf16)a[2].x; st.h[5] = (bf16)a[2].y;
        st.h[6] = (bf16)a[3].x; st.h[7] = (bf16)a[3].y;
        *(uint4*)(hout + (size_t)n * HID + slice * SLB + il * 8) = st.u;
    }
}

// ---------------------------------------------------------------------------
// Head: logits = h @ W2 + b2 via MFMA (N=64, cols>=40 zero), fused log_softmax.
// ---------------------------------------------------------------------------
__global__ __launch_bounds__(256) void head_mfma(
    const bf16* __restrict__ h, const bf16* __restrict__ Wt2,
    const float* __restrict__ b2, float* __restrict__ out, int M)
{
    constexpr int K = HID, LDB = K + 8;
    __shared__ bf16 Bs[64 * LDB];

    const int tid = threadIdx.x;
    constexpr int CPR = K / 8;
    for (int f = tid; f < 64 * CPR; f += 256) {
        int row = f / CPR;
        int kc  = (f % CPR) * 8;
        *(uint4*)&Bs[row * LDB + kc] = *(const uint4*)(Wt2 + (size_t)row * K + kc);
    }
    __syncthreads();

    const int wv   = tid >> 6;
    const int lane = tid & 63;
    const int l31  = lane & 31;
    const int lhi  = lane >> 5;
    const int blockRow = blockIdx.x * 128;
    const int arow = min(blockRow + wv * 32 + l31, M - 1);

    f32x16 acc[2];
#pragma unroll
    for (int t = 0; t < 2; ++t)
#pragma unroll
        for (int r = 0; r < 16; ++r) acc[t][r] = 0.0f;

#pragma unroll
    for (int ks = 0; ks < K / 16; ++ks) {
        bf16x8 a = *(const bf16x8*)(h + (size_t)arow * K + ks * 16 + lhi * 8);
#pragma unroll
        for (int t = 0; t < 2; ++t) {
            bf16x8 b = *(const bf16x8*)&Bs[(t * 32 + l31) * LDB + ks * 16 + lhi * 8];
            acc[t] = __builtin_amdgcn_mfma_f32_32x32x16_bf16(a, b, acc[t], 0, 0, 0);
        }
    }

    const float bc0 = b2[l31];
    const float bc1 = (l31 < 8) ? b2[32 + l31] : 0.0f;

#pragma unroll
    for (int r = 0; r < 16; ++r) {
        float v0 = acc[0][r] + bc0;
        float v1 = (l31 < 8) ? (acc[1][r] + bc1) : -INFINITY;

        float m = fmaxf(v0, v1);
#pragma unroll
        for (int off = 16; off > 0; off >>= 1)
            m = fmaxf(m, __shfl_xor(m, off, 64));

        float s = __expf(v0 - m) + ((l31 < 8) ? __expf(v1 - m) : 0.0f);
#pragma unroll
        for (int off = 16; off > 0; off >>= 1)
            s += __shfl_xor(s, off, 64);

        float ls = __logf(s);
        int grow = blockRow + wv * 32 + (r & 3) + 8 * (r >> 2) + 4 * lhi;
        if (grow < M) {
            out[(size_t)grow * NCLS + l31] = v0 - m - ls;
            if (l31 < 8)
                out[(size_t)grow * NCLS + 32 + l31] = v1 - m - ls;
        }
    }
}

extern "C" void kernel_launch(void* const* d_in, const int* in_sizes, int n_in,
                              void* d_out, int out_size, void* d_ws, size_t ws_size,
                              hipStream_t stream)
{
    const float* x      = (const float*)d_in[0];
    const float* degree = (const float*)d_in[1];
    const int*   ends   = (const int*)  d_in[2];
    const float* att    = (const float*)d_in[3];
    const float* W0     = (const float*)d_in[4];
    const float* b0     = (const float*)d_in[5];
    const float* W1     = (const float*)d_in[6];
    const float* b1     = (const float*)d_in[7];
    const float* W2     = (const float*)d_in[8];
    const float* b2     = (const float*)d_in[9];
    float* out = (float*)d_out;

    bf16* hb0 = (bf16*)d_ws;                               // [NNODES, HID] bf16
    bf16* hb1 = hb0 + (size_t)NNODES * HID;                // [NNODES, HID] bf16
    unsigned char* hf8 = (unsigned char*)(hb1 + (size_t)NNODES * HID);  // [NSLICE][NNODES][SLB] fp8
    bf16* Wt0 = (bf16*)(hf8 + (size_t)NNODES * HID);       // [128, 256]
    bf16* Wt1 = Wt0 + 128 * 256;                           // [128, 128]
    bf16* Wt2 = Wt1 + 128 * 128;                           // [64, 128]

    const int prepN = 128 * 256 + 128 * 128 + 64 * 128;
    prep_w<<<(prepN + 255) / 256, 256, 0, stream>>>(W0, W1, W2, Wt0, Wt1, Wt2);

    const int gGemm = (NNODES + 127) / 128;
    const int gAgg  = NSLICE * NBAGG;   // slice outer-major

    // layer 0
    gemm_nodes<NFEAT, false><<<gGemm, 256, 0, stream>>>(x, Wt0, b0, hf8, NNODES);
    agg_relu_fp8<<<gAgg, 256, 0, stream>>>(hf8, hb1, ends, degree, att);
    // layer 1
    gemm_nodes<HID, true><<<gGemm, 256, 0, stream>>>(hb1, Wt1, b1, hf8, NNODES);
    agg_relu_fp8<<<gAgg, 256, 0, stream>>>(
        hf8, hb0, ends + (size_t)KHOP * NNODES * RWSAMP, degree, att + KP1);
    // head
    head_mfma<<<gGemm, 256, 0, stream>>>(hb0, Wt2, b2, out, NNODES);
}

// Round 6
// 358.934 us; speedup vs baseline: 1.4672x; 1.4672x over previous
//
#include <hip/hip_runtime.h>
#include <math.h>

#define NNODES 100000
#define NFEAT  256
#define HID    128
#define NCLS   40
#define KHOP   4
#define RWSAMP 10
#define KP1    5

typedef __bf16 bf16;
typedef __attribute__((ext_vector_type(8)))  __bf16 bf16x8;
typedef __attribute__((ext_vector_type(2)))  float  f32x2;
typedef __attribute__((ext_vector_type(16))) float  f32x16;

// ---------------------------------------------------------------------------
// Prep: transpose+convert weights to bf16 [n][k] layout.
// ---------------------------------------------------------------------------
__global__ __launch_bounds__(256) void prep_w(
    const float* __restrict__ W0, const float* __restrict__ W1,
    const float* __restrict__ W2,
    bf16* __restrict__ Wt0, bf16* __restrict__ Wt1, bf16* __restrict__ Wt2)
{
    int tid = blockIdx.x * 256 + threadIdx.x;
    if (tid < 128 * 256) {
        int n = tid >> 8, k = tid & 255;
        Wt0[tid] = (bf16)W0[k * 128 + n];
    } else if (tid < 128 * 256 + 128 * 128) {
        int i = tid - 128 * 256;
        int n = i >> 7, k = i & 127;
        Wt1[i] = (bf16)W1[k * 128 + n];
    } else if (tid < 128 * 256 + 128 * 128 + 64 * 128) {
        int i = tid - (128 * 256 + 128 * 128);
        int n = i >> 7, k = i & 127;
        Wt2[i] = (n < NCLS) ? (bf16)W2[k * NCLS + n] : (bf16)0.0f;
    }
}

// ---------------------------------------------------------------------------
// GEMM: MFMA 32x32x16 bf16; output a row-major fp8-e4m3 table that is
// PRE-SCALED by rsqrt(degree[row])  (R12: kills the per-walk degree[e]
// gather in agg -- 4M random line-probes per dispatch, ~43% of all probes).
// fp8 is a float format, so pre-scaling preserves relative precision.
// ---------------------------------------------------------------------------
template<int K, bool A_BF16>
__global__ __launch_bounds__(256) void gemm_nodes(
    const void* __restrict__ Av, const bf16* __restrict__ Wt,
    const float* __restrict__ bias, const float* __restrict__ degree,
    unsigned char* __restrict__ F8, int M)
{
    constexpr int BK  = 128;
    constexpr int LDB = BK + 4;
    __shared__ bf16 Bs[128 * LDB];
    __shared__ bf16 As[4][32 * LDB];

    const int tid  = threadIdx.x;
    const int wv   = tid >> 6;
    const int lane = tid & 63;
    const int l31  = lane & 31;
    const int lhi  = lane >> 5;
    const int blockRow = blockIdx.x * 128;
    const int rowBase  = blockRow + wv * 32;

    const bf16*  Ab = (const bf16*)Av;
    const float* Af = (const float*)Av;

    f32x16 acc[4];
#pragma unroll
    for (int t = 0; t < 4; ++t)
#pragma unroll
        for (int r = 0; r < 16; ++r) acc[t][r] = 0.0f;

    for (int k0 = 0; k0 < K; k0 += BK) {
        if (k0) __syncthreads();
#pragma unroll 4
        for (int l = 0; l < 8; ++l) {
            int c   = tid + l * 256;
            int row = c >> 4;
            int kc  = (c & 15) * 8;
            uint4 v = *(const uint4*)(Wt + (size_t)row * K + k0 + kc);
            *(uint2*)&Bs[row * LDB + kc]     = make_uint2(v.x, v.y);
            *(uint2*)&Bs[row * LDB + kc + 4] = make_uint2(v.z, v.w);
        }
        __syncthreads();

        if (A_BF16) {
#pragma unroll 4
            for (int l = 0; l < 8; ++l) {
                int c  = lane + l * 64;
                int r  = c >> 4;
                int kc = (c & 15) * 8;
                int gr = min(rowBase + r, M - 1);
                uint4 v = *(const uint4*)(Ab + (size_t)gr * K + k0 + kc);
                *(uint2*)&As[wv][r * LDB + kc]     = make_uint2(v.x, v.y);
                *(uint2*)&As[wv][r * LDB + kc + 4] = make_uint2(v.z, v.w);
            }
        } else {
#pragma unroll 4
            for (int l = 0; l < 16; ++l) {
                int c  = lane + l * 64;
                int r  = c >> 5;
                int kc = (c & 31) * 4;
                int gr = min(rowBase + r, M - 1);
                float4 v = *(const float4*)(Af + (size_t)gr * K + k0 + kc);
                union { bf16 h[4]; uint2 u; } t4;
                t4.h[0] = (bf16)v.x; t4.h[1] = (bf16)v.y;
                t4.h[2] = (bf16)v.z; t4.h[3] = (bf16)v.w;
                *(uint2*)&As[wv][r * LDB + kc] = t4.u;
            }
        }

#pragma unroll
        for (int ks = 0; ks < BK / 16; ++ks) {
            const int ko = ks * 16 + lhi * 8;
            union { uint2 u2[2]; bf16x8 v; } ua, ub;
            ua.u2[0] = *(const uint2*)&As[wv][l31 * LDB + ko];
            ua.u2[1] = *(const uint2*)&As[wv][l31 * LDB + ko + 4];
            bf16x8 a = ua.v;
#pragma unroll
            for (int t = 0; t < 4; ++t) {
                ub.u2[0] = *(const uint2*)&Bs[(t * 32 + l31) * LDB + ko];
                ub.u2[1] = *(const uint2*)&Bs[(t * 32 + l31) * LDB + ko + 4];
                acc[t] = __builtin_amdgcn_mfma_f32_32x32x16_bf16(a, ub.v, acc[t], 0, 0, 0);
            }
        }
    }

    // rsqrt(degree) for the 16 rows this thread packs (uniform across cols,
    // streaming loads -> scalarized; degree in (1,64] so always finite).
    float rsd[16];
#pragma unroll
    for (int G = 0; G < 4; ++G) {
        int r0 = blockRow + 4 * (wv * 8 + 2 * G + lhi);
#pragma unroll
        for (int c = 0; c < 4; ++c)
            rsd[4 * G + c] = rsqrtf(degree[min(r0 + c, M - 1)]);
    }

    __syncthreads();
    unsigned* ldsq = (unsigned*)Bs;   // [32 rowquads][128 cols]

#pragma unroll
    for (int t = 0; t < 4; ++t) {
        int col = t * 32 + l31;
        float bc = bias[col];
#pragma unroll
        for (int G = 0; G < 4; ++G) {
            float v0 = (acc[t][4 * G + 0] + bc) * rsd[4 * G + 0];
            float v1 = (acc[t][4 * G + 1] + bc) * rsd[4 * G + 1];
            float v2 = (acc[t][4 * G + 2] + bc) * rsd[4 * G + 2];
            float v3 = (acc[t][4 * G + 3] + bc) * rsd[4 * G + 3];
            int p = __builtin_amdgcn_cvt_pk_fp8_f32(v0, v1, 0, false);
            p = __builtin_amdgcn_cvt_pk_fp8_f32(v2, v3, p, true);
            ldsq[(wv * 8 + 2 * G + lhi) * 128 + col] = (unsigned)p;
        }
    }
    __syncthreads();

    {
        const int j  = tid & 31;
        const int Q0 = (tid >> 5) * 4;
#pragma unroll
        for (int qq = 0; qq < 4; ++qq) {
            int Q = Q0 + qq;
            uint4 d = *(const uint4*)&ldsq[Q * 128 + 4 * j];
            int growb = blockRow + 4 * Q;
#pragma unroll
            for (int i = 0; i < 4; ++i) {
                unsigned sel = ((unsigned)(4 + i) << 8) | (unsigned)i;
                unsigned lo = __builtin_amdgcn_perm(d.y, d.x, sel);
                unsigned hi = __builtin_amdgcn_perm(d.w, d.z, sel);
                unsigned o  = __builtin_amdgcn_perm(hi, lo, 0x05040100u);
                if (growb + i < M)
                    *(unsigned*)(F8 + (size_t)(growb + i) * 128 + 4 * j) = o;
            }
        }
    }
}

// ---------------------------------------------------------------------------
// Aggregation + ReLU (R12). ONE NODE PER WAVE.
// Evidence R0-R5: dur tracks random-LINE-PROBE count, not miss bytes (R5:
// -36% FETCH but 2.3x probes -> 2.3x slower) and not wave-MLP (R4). So:
// (1) uint4 gathers, 8 lanes/row -> 1 KB & 8 probes per instr (probes/byte
//     halves vs R0) with explicit one-ahead prefetch (2 KB in flight/wave);
// (2) table is pre-scaled by rsqrt(degree) in the GEMM -> NO degree[e]
//     gathers (was 4M probes/dispatch); all walk weights = att[k+1]/RWS
//     broadcast; sqrt(degree[n]) applied once after reduction.
// Slots s=0..7 each own one row/instr; t=0..5 covers 48 slots: j<40 walks,
// j==40 self (weight att0), j>40 pad = self row with w=0 (same cache line,
// coalesces free). Lane fc=lane&7 owns features fc*16..fc*16+15.
// ---------------------------------------------------------------------------
__global__ __launch_bounds__(256) void agg_relu_fp8(
    const unsigned char* __restrict__ hf8, bf16* __restrict__ hout,
    const int* __restrict__ ends, const float* __restrict__ degree,
    const float* __restrict__ att)
{
    __shared__ int   sewE[4][48];
    __shared__ float sewW[4][48];

    const int wv   = threadIdx.x >> 6;
    const int lane = threadIdx.x & 63;
    const int n    = blockIdx.x * 4 + wv;     // one node per wave

    if (lane < 48) {
        int j = lane;
        int e; float w;
        if (j < 40) {
            int k = j / RWSAMP, ss = j - k * RWSAMP;
            e = ends[(size_t)k * (NNODES * RWSAMP) + (size_t)n * RWSAMP + ss];
            w = att[k + 1] * (1.0f / RWSAMP);
        } else if (j == 40) { e = n; w = att[0]; }
        else                { e = n; w = 0.0f;  }
        sewE[wv][j] = e << 7;                  // byte offset of 128B row
        sewW[wv][j] = w;
    }
    // wave-private LDS: same-wave producer/consumer, in-order DS pipe

    const int s  = lane >> 3;                  // row slot 0..7
    const int fc = lane & 7;                   // feature chunk (16B)

    int   eoff[6];
    float wt[6];
#pragma unroll
    for (int t = 0; t < 6; ++t) {
        eoff[t] = sewE[wv][8 * t + s];
        wt[t]   = sewW[wv][8 * t + s];
    }

    const unsigned char* base = hf8 + (unsigned)(fc * 16);
    uint4 cur = *(const uint4*)(base + (unsigned)eoff[0]);

    f32x2 acc[8];
#pragma unroll
    for (int i = 0; i < 8; ++i) acc[i] = (f32x2){0.f, 0.f};

#pragma unroll
    for (int t = 0; t < 6; ++t) {
        uint4 nxt = cur;
        if (t < 5) nxt = *(const uint4*)(base + (unsigned)eoff[t + 1]);
        float w = wt[t];
        f32x2 w2 = {w, w};
        acc[0] = __builtin_elementwise_fma(w2, __builtin_amdgcn_cvt_pk_f32_fp8((int)cur.x, false), acc[0]);
        acc[1] = __builtin_elementwise_fma(w2, __builtin_amdgcn_cvt_pk_f32_fp8((int)cur.x, true),  acc[1]);
        acc[2] = __builtin_elementwise_fma(w2, __builtin_amdgcn_cvt_pk_f32_fp8((int)cur.y, false), acc[2]);
        acc[3] = __builtin_elementwise_fma(w2, __builtin_amdgcn_cvt_pk_f32_fp8((int)cur.y, true),  acc[3]);
        acc[4] = __builtin_elementwise_fma(w2, __builtin_amdgcn_cvt_pk_f32_fp8((int)cur.z, false), acc[4]);
        acc[5] = __builtin_elementwise_fma(w2, __builtin_amdgcn_cvt_pk_f32_fp8((int)cur.z, true),  acc[5]);
        acc[6] = __builtin_elementwise_fma(w2, __builtin_amdgcn_cvt_pk_f32_fp8((int)cur.w, false), acc[6]);
        acc[7] = __builtin_elementwise_fma(w2, __builtin_amdgcn_cvt_pk_f32_fp8((int)cur.w, true),  acc[7]);
        cur = nxt;
    }

    // reduce across the 8 row-slots (lanes strided by 8): xor 8,16,32
#pragma unroll
    for (int i = 0; i < 8; ++i) {
        acc[i].x += __shfl_xor(acc[i].x, 8, 64);  acc[i].y += __shfl_xor(acc[i].y, 8, 64);
        acc[i].x += __shfl_xor(acc[i].x, 16, 64); acc[i].y += __shfl_xor(acc[i].y, 16, 64);
        acc[i].x += __shfl_xor(acc[i].x, 32, 64); acc[i].y += __shfl_xor(acc[i].y, 32, 64);
    }

    if (s == 0) {
        float sd = sqrtf(degree[n]);           // un-do the table pre-scale
        f32x2 sd2 = {sd, sd}, z = {0.f, 0.f};
#pragma unroll
        for (int i = 0; i < 8; ++i) {
            acc[i] = __builtin_elementwise_max(acc[i], z);  // relu commutes
            acc[i] = acc[i] * sd2;                          // with sd>0
        }
        union { bf16 h[8]; uint4 u; } lo, hi;
        lo.h[0] = (bf16)acc[0].x; lo.h[1] = (bf16)acc[0].y;
        lo.h[2] = (bf16)acc[1].x; lo.h[3] = (bf16)acc[1].y;
        lo.h[4] = (bf16)acc[2].x; lo.h[5] = (bf16)acc[2].y;
        lo.h[6] = (bf16)acc[3].x; lo.h[7] = (bf16)acc[3].y;
        hi.h[0] = (bf16)acc[4].x; hi.h[1] = (bf16)acc[4].y;
        hi.h[2] = (bf16)acc[5].x; hi.h[3] = (bf16)acc[5].y;
        hi.h[4] = (bf16)acc[6].x; hi.h[5] = (bf16)acc[6].y;
        hi.h[6] = (bf16)acc[7].x; hi.h[7] = (bf16)acc[7].y;
        bf16* orow = hout + (size_t)n * HID + fc * 16;
        *(uint4*)orow       = lo.u;
        *(uint4*)(orow + 8) = hi.u;
    }
}

// ---------------------------------------------------------------------------
// Head: logits = h @ W2 + b2 via MFMA (N=64, cols>=40 zero), fused log_softmax.
// ---------------------------------------------------------------------------
__global__ __launch_bounds__(256) void head_mfma(
    const bf16* __restrict__ h, const bf16* __restrict__ Wt2,
    const float* __restrict__ b2, float* __restrict__ out, int M)
{
    constexpr int K = HID, LDB = K + 8;
    __shared__ bf16 Bs[64 * LDB];

    const int tid = threadIdx.x;
    constexpr int CPR = K / 8;
    for (int f = tid; f < 64 * CPR; f += 256) {
        int row = f / CPR;
        int kc  = (f % CPR) * 8;
        *(uint4*)&Bs[row * LDB + kc] = *(const uint4*)(Wt2 + (size_t)row * K + kc);
    }
    __syncthreads();

    const int wv   = tid >> 6;
    const int lane = tid & 63;
    const int l31  = lane & 31;
    const int lhi  = lane >> 5;
    const int blockRow = blockIdx.x * 128;
    const int arow = min(blockRow + wv * 32 + l31, M - 1);

    f32x16 acc[2];
#pragma unroll
    for (int t = 0; t < 2; ++t)
#pragma unroll
        for (int r = 0; r < 16; ++r) acc[t][r] = 0.0f;

#pragma unroll
    for (int ks = 0; ks < K / 16; ++ks) {
        bf16x8 a = *(const bf16x8*)(h + (size_t)arow * K + ks * 16 + lhi * 8);
#pragma unroll
        for (int t = 0; t < 2; ++t) {
            bf16x8 b = *(const bf16x8*)&Bs[(t * 32 + l31) * LDB + ks * 16 + lhi * 8];
            acc[t] = __builtin_amdgcn_mfma_f32_32x32x16_bf16(a, b, acc[t], 0, 0, 0);
        }
    }

    const float bc0 = b2[l31];
    const float bc1 = (l31 < 8) ? b2[32 + l31] : 0.0f;

#pragma unroll
    for (int r = 0; r < 16; ++r) {
        float v0 = acc[0][r] + bc0;
        float v1 = (l31 < 8) ? (acc[1][r] + bc1) : -INFINITY;

        float m = fmaxf(v0, v1);
#pragma unroll
        for (int off = 16; off > 0; off >>= 1)
            m = fmaxf(m, __shfl_xor(m, off, 64));

        float s = __expf(v0 - m) + ((l31 < 8) ? __expf(v1 - m) : 0.0f);
#pragma unroll
        for (int off = 16; off > 0; off >>= 1)
            s += __shfl_xor(s, off, 64);

        float ls = __logf(s);
        int grow = blockRow + wv * 32 + (r & 3) + 8 * (r >> 2) + 4 * lhi;
        if (grow < M) {
            out[(size_t)grow * NCLS + l31] = v0 - m - ls;
            if (l31 < 8)
                out[(size_t)grow * NCLS + 32 + l31] = v1 - m - ls;
        }
    }
}

extern "C" void kernel_launch(void* const* d_in, const int* in_sizes, int n_in,
                              void* d_out, int out_size, void* d_ws, size_t ws_size,
                              hipStream_t stream)
{
    const float* x      = (const float*)d_in[0];
    const float* degree = (const float*)d_in[1];
    const int*   ends   = (const int*)  d_in[2];
    const float* att    = (const float*)d_in[3];
    const float* W0     = (const float*)d_in[4];
    const float* b0     = (const float*)d_in[5];
    const float* W1     = (const float*)d_in[6];
    const float* b1     = (const float*)d_in[7];
    const float* W2     = (const float*)d_in[8];
    const float* b2     = (const float*)d_in[9];
    float* out = (float*)d_out;

    bf16* hb0 = (bf16*)d_ws;                               // [NNODES, HID] bf16
    bf16* hb1 = hb0 + (size_t)NNODES * HID;                // [NNODES, HID] bf16
    unsigned char* hf8 = (unsigned char*)(hb1 + (size_t)NNODES * HID);  // [NNODES,128] fp8 (rsqrt-scaled)
    bf16* Wt0 = (bf16*)(hf8 + (size_t)NNODES * HID);       // [128, 256]
    bf16* Wt1 = Wt0 + 128 * 256;                           // [128, 128]
    bf16* Wt2 = Wt1 + 128 * 128;                           // [64, 128]

    const int prepN = 128 * 256 + 128 * 128 + 64 * 128;
    prep_w<<<(prepN + 255) / 256, 256, 0, stream>>>(W0, W1, W2, Wt0, Wt1, Wt2);

    const int gGemm = (NNODES + 127) / 128;
    const int gAgg  = NNODES / 4;              // one node per wave, 4 waves/block

    // layer 0
    gemm_nodes<NFEAT, false><<<gGemm, 256, 0, stream>>>(x, Wt0, b0, degree, hf8, NNODES);
    agg_relu_fp8<<<gAgg, 256, 0, stream>>>(hf8, hb1, ends, degree, att);
    // layer 1
    gemm_nodes<HID, true><<<gGemm, 256, 0, stream>>>(hb1, Wt1, b1, degree, hf8, NNODES);
    agg_relu_fp8<<<gAgg, 256, 0, stream>>>(
        hf8, hb0, ends + (size_t)KHOP * NNODES * RWSAMP, degree, att + KP1);
    // head
    head_mfma<<<gGemm, 256, 0, stream>>>(hb0, Wt2, b2, out, NNODES);
}

// Round 7
// 333.753 us; speedup vs baseline: 1.5779x; 1.0754x over previous
//
#include <hip/hip_runtime.h>
#include <math.h>

#define NNODES 100000
#define NFEAT  256
#define HID    128
#define NCLS   40
#define KHOP   4
#define RWSAMP 10
#define KP1    5

typedef __bf16 bf16;
typedef __attribute__((ext_vector_type(8)))  __bf16 bf16x8;
typedef __attribute__((ext_vector_type(2)))  float  f32x2;
typedef __attribute__((ext_vector_type(16))) float  f32x16;

// ---------------------------------------------------------------------------
// Prep: transpose+convert weights to bf16 [n][k] layout.
// ---------------------------------------------------------------------------
__global__ __launch_bounds__(256) void prep_w(
    const float* __restrict__ W0, const float* __restrict__ W1,
    const float* __restrict__ W2,
    bf16* __restrict__ Wt0, bf16* __restrict__ Wt1, bf16* __restrict__ Wt2)
{
    int tid = blockIdx.x * 256 + threadIdx.x;
    if (tid < 128 * 256) {
        int n = tid >> 8, k = tid & 255;
        Wt0[tid] = (bf16)W0[k * 128 + n];
    } else if (tid < 128 * 256 + 128 * 128) {
        int i = tid - 128 * 256;
        int n = i >> 7, k = i & 127;
        Wt1[i] = (bf16)W1[k * 128 + n];
    } else if (tid < 128 * 256 + 128 * 128 + 64 * 128) {
        int i = tid - (128 * 256 + 128 * 128);
        int n = i >> 7, k = i & 127;
        Wt2[i] = (n < NCLS) ? (bf16)W2[k * NCLS + n] : (bf16)0.0f;
    }
}

// ---------------------------------------------------------------------------
// GEMM: MFMA 32x32x16 bf16; output a row-major fp8-e4m3 table PRE-SCALED by
// rsqrt(degree[row]) (R12-proven: kills all degree[e] gathers in agg; fp8 is
// a float format so prescaling preserves relative precision; absmax was
// bit-identical to the unscaled version).
// ---------------------------------------------------------------------------
template<int K, bool A_BF16>
__global__ __launch_bounds__(256) void gemm_nodes(
    const void* __restrict__ Av, const bf16* __restrict__ Wt,
    const float* __restrict__ bias, const float* __restrict__ degree,
    unsigned char* __restrict__ F8, int M)
{
    constexpr int BK  = 128;
    constexpr int LDB = BK + 4;
    __shared__ bf16 Bs[128 * LDB];
    __shared__ bf16 As[4][32 * LDB];

    const int tid  = threadIdx.x;
    const int wv   = tid >> 6;
    const int lane = tid & 63;
    const int l31  = lane & 31;
    const int lhi  = lane >> 5;
    const int blockRow = blockIdx.x * 128;
    const int rowBase  = blockRow + wv * 32;

    const bf16*  Ab = (const bf16*)Av;
    const float* Af = (const float*)Av;

    f32x16 acc[4];
#pragma unroll
    for (int t = 0; t < 4; ++t)
#pragma unroll
        for (int r = 0; r < 16; ++r) acc[t][r] = 0.0f;

    for (int k0 = 0; k0 < K; k0 += BK) {
        if (k0) __syncthreads();
#pragma unroll 4
        for (int l = 0; l < 8; ++l) {
            int c   = tid + l * 256;
            int row = c >> 4;
            int kc  = (c & 15) * 8;
            uint4 v = *(const uint4*)(Wt + (size_t)row * K + k0 + kc);
            *(uint2*)&Bs[row * LDB + kc]     = make_uint2(v.x, v.y);
            *(uint2*)&Bs[row * LDB + kc + 4] = make_uint2(v.z, v.w);
        }
        __syncthreads();

        if (A_BF16) {
#pragma unroll 4
            for (int l = 0; l < 8; ++l) {
                int c  = lane + l * 64;
                int r  = c >> 4;
                int kc = (c & 15) * 8;
                int gr = min(rowBase + r, M - 1);
                uint4 v = *(const uint4*)(Ab + (size_t)gr * K + k0 + kc);
                *(uint2*)&As[wv][r * LDB + kc]     = make_uint2(v.x, v.y);
                *(uint2*)&As[wv][r * LDB + kc + 4] = make_uint2(v.z, v.w);
            }
        } else {
#pragma unroll 4
            for (int l = 0; l < 16; ++l) {
                int c  = lane + l * 64;
                int r  = c >> 5;
                int kc = (c & 31) * 4;
                int gr = min(rowBase + r, M - 1);
                float4 v = *(const float4*)(Af + (size_t)gr * K + k0 + kc);
                union { bf16 h[4]; uint2 u; } t4;
                t4.h[0] = (bf16)v.x; t4.h[1] = (bf16)v.y;
                t4.h[2] = (bf16)v.z; t4.h[3] = (bf16)v.w;
                *(uint2*)&As[wv][r * LDB + kc] = t4.u;
            }
        }

#pragma unroll
        for (int ks = 0; ks < BK / 16; ++ks) {
            const int ko = ks * 16 + lhi * 8;
            union { uint2 u2[2]; bf16x8 v; } ua, ub;
            ua.u2[0] = *(const uint2*)&As[wv][l31 * LDB + ko];
            ua.u2[1] = *(const uint2*)&As[wv][l31 * LDB + ko + 4];
            bf16x8 a = ua.v;
#pragma unroll
            for (int t = 0; t < 4; ++t) {
                ub.u2[0] = *(const uint2*)&Bs[(t * 32 + l31) * LDB + ko];
                ub.u2[1] = *(const uint2*)&Bs[(t * 32 + l31) * LDB + ko + 4];
                acc[t] = __builtin_amdgcn_mfma_f32_32x32x16_bf16(a, ub.v, acc[t], 0, 0, 0);
            }
        }
    }

    // rsqrt(degree) for the 16 rows this thread packs (degree in (1,64]).
    float rsd[16];
#pragma unroll
    for (int G = 0; G < 4; ++G) {
        int r0 = blockRow + 4 * (wv * 8 + 2 * G + lhi);
#pragma unroll
        for (int c = 0; c < 4; ++c)
            rsd[4 * G + c] = rsqrtf(degree[min(r0 + c, M - 1)]);
    }

    __syncthreads();
    unsigned* ldsq = (unsigned*)Bs;   // [32 rowquads][128 cols]

#pragma unroll
    for (int t = 0; t < 4; ++t) {
        int col = t * 32 + l31;
        float bc = bias[col];
#pragma unroll
        for (int G = 0; G < 4; ++G) {
            float v0 = (acc[t][4 * G + 0] + bc) * rsd[4 * G + 0];
            float v1 = (acc[t][4 * G + 1] + bc) * rsd[4 * G + 1];
            float v2 = (acc[t][4 * G + 2] + bc) * rsd[4 * G + 2];
            float v3 = (acc[t][4 * G + 3] + bc) * rsd[4 * G + 3];
            int p = __builtin_amdgcn_cvt_pk_fp8_f32(v0, v1, 0, false);
            p = __builtin_amdgcn_cvt_pk_fp8_f32(v2, v3, p, true);
            ldsq[(wv * 8 + 2 * G + lhi) * 128 + col] = (unsigned)p;
        }
    }
    __syncthreads();

    {
        const int j  = tid & 31;
        const int Q0 = (tid >> 5) * 4;
#pragma unroll
        for (int qq = 0; qq < 4; ++qq) {
            int Q = Q0 + qq;
            uint4 d = *(const uint4*)&ldsq[Q * 128 + 4 * j];
            int growb = blockRow + 4 * Q;
#pragma unroll
            for (int i = 0; i < 4; ++i) {
                unsigned sel = ((unsigned)(4 + i) << 8) | (unsigned)i;
                unsigned lo = __builtin_amdgcn_perm(d.y, d.x, sel);
                unsigned hi = __builtin_amdgcn_perm(d.w, d.z, sel);
                unsigned o  = __builtin_amdgcn_perm(hi, lo, 0x05040100u);
                if (growb + i < M)
                    *(unsigned*)(F8 + (size_t)(growb + i) * 128 + 4 * j) = o;
            }
        }
    }
}

// ---------------------------------------------------------------------------
// Aggregation + ReLU (R13). ONE WAVE = TWO NODES, quarter-gather geometry.
// Model from R0-R6: dur = line-bytes / ~7.8 TB/s (random-gather L2 service
// rate), given occupancy and full-line requests. So: minimize line-bytes at
// fp8 = R0 geometry (full 128B rows, no pads) + prescaled table (NO degree
// gathers: was 40 random 4B-line probes per node). Weights are now node-
// independent (att[k+1]/RWS) from a 44-entry block-shared LDS table; self
// handled as loop step t=10 where all 4 quarters read the same line (w =
// att0 for q0, 0 for q1..3); sqrt(degree[n]) applied once post-reduction
// (relu commutes with positive scale).
// ---------------------------------------------------------------------------
__global__ __launch_bounds__(256) void agg_relu_fp8(
    const unsigned char* __restrict__ hf8, bf16* __restrict__ hout,
    const int* __restrict__ ends, const float* __restrict__ degree,
    const float* __restrict__ att)
{
    __shared__ int   sewE[4][2][40];   // [wave][node][walk] = e<<7
    __shared__ float sw[44];           // block-shared weights (node-indep)

    const int wv   = threadIdx.x >> 6;
    const int lane = threadIdx.x & 63;
    const int n0   = blockIdx.x * 8 + wv * 2;   // wave handles n0, n0+1

    if (threadIdx.x < 44) {
        int j = threadIdx.x;
        float w;
        if (j < 40)       w = att[j / RWSAMP + 1] * (1.0f / RWSAMP);
        else if (j == 40) w = att[0];
        else              w = 0.0f;
        sw[j] = w;
    }

    for (int en = lane; en < 80; en += 64) {
        int which = en >= 40;
        int l = en - which * 40;
        int n = n0 + which;
        int k = l / RWSAMP, s = l - k * RWSAMP;
        int e = ends[(size_t)k * (NNODES * RWSAMP) + (size_t)n * RWSAMP + s];
        sewE[wv][which][l] = e << 7;
    }
    __syncthreads();   // sw is block-shared (sewE is wave-private, in-order DS)

    const int q  = lane >> 4;
    const int c8 = (lane & 15) * 8;

    f32x2 a0[4], a1[4];
#pragma unroll
    for (int i = 0; i < 4; ++i) { a0[i] = (f32x2){0.f, 0.f}; a1[i] = (f32x2){0.f, 0.f}; }

#pragma unroll
    for (int t = 0; t < 11; ++t) {
        int j = 4 * t + q;                       // t=10 -> j=40+q (self/pad)
        int e0, e1;
        if (t < 10) { e0 = sewE[wv][0][j]; e1 = sewE[wv][1][j]; }
        else        { e0 = n0 << 7;        e1 = (n0 + 1) << 7; }
        float w = sw[j];
        uint2 g0 = *(const uint2*)(hf8 + (unsigned)e0 + (unsigned)c8);
        uint2 g1 = *(const uint2*)(hf8 + (unsigned)e1 + (unsigned)c8);
        f32x2 w2 = {w, w};
        a0[0] = __builtin_elementwise_fma(w2, __builtin_amdgcn_cvt_pk_f32_fp8((int)g0.x, false), a0[0]);
        a0[1] = __builtin_elementwise_fma(w2, __builtin_amdgcn_cvt_pk_f32_fp8((int)g0.x, true),  a0[1]);
        a0[2] = __builtin_elementwise_fma(w2, __builtin_amdgcn_cvt_pk_f32_fp8((int)g0.y, false), a0[2]);
        a0[3] = __builtin_elementwise_fma(w2, __builtin_amdgcn_cvt_pk_f32_fp8((int)g0.y, true),  a0[3]);
        a1[0] = __builtin_elementwise_fma(w2, __builtin_amdgcn_cvt_pk_f32_fp8((int)g1.x, false), a1[0]);
        a1[1] = __builtin_elementwise_fma(w2, __builtin_amdgcn_cvt_pk_f32_fp8((int)g1.x, true),  a1[1]);
        a1[2] = __builtin_elementwise_fma(w2, __builtin_amdgcn_cvt_pk_f32_fp8((int)g1.y, false), a1[2]);
        a1[3] = __builtin_elementwise_fma(w2, __builtin_amdgcn_cvt_pk_f32_fp8((int)g1.y, true),  a1[3]);
    }

    // combine quarters (xor 16, 32) for both nodes
#pragma unroll
    for (int i = 0; i < 4; ++i) {
        a0[i].x += __shfl_xor(a0[i].x, 16, 64); a0[i].y += __shfl_xor(a0[i].y, 16, 64);
        a1[i].x += __shfl_xor(a1[i].x, 16, 64); a1[i].y += __shfl_xor(a1[i].y, 16, 64);
        a0[i].x += __shfl_xor(a0[i].x, 32, 64); a0[i].y += __shfl_xor(a0[i].y, 32, 64);
        a1[i].x += __shfl_xor(a1[i].x, 32, 64); a1[i].y += __shfl_xor(a1[i].y, 32, 64);
    }

    if (q < 2) {
        // quarter 0 -> node0, quarter 1 -> node1
        const int n = n0 + q;
        f32x2* a = (q == 0) ? a0 : a1;
        float sd = sqrtf(degree[n]);             // un-do the table pre-scale
        f32x2 sd2 = {sd, sd}, z = {0.f, 0.f};
#pragma unroll
        for (int i = 0; i < 4; ++i) {
            a[i] = __builtin_elementwise_max(a[i], z);   // relu commutes
            a[i] = a[i] * sd2;                           // with sd>0
        }

        union { bf16 h[8]; uint4 u; } st;
        st.h[0] = (bf16)a[0].x; st.h[1] = (bf16)a[0].y;
        st.h[2] = (bf16)a[1].x; st.h[3] = (bf16)a[1].y;
        st.h[4] = (bf16)a[2].x; st.h[5] = (bf16)a[2].y;
        st.h[6] = (bf16)a[3].x; st.h[7] = (bf16)a[3].y;
        *(uint4*)(hout + (size_t)n * HID + c8) = st.u;
    }
}

// ---------------------------------------------------------------------------
// Head: logits = h @ W2 + b2 via MFMA (N=64, cols>=40 zero), fused log_softmax.
// ---------------------------------------------------------------------------
__global__ __launch_bounds__(256) void head_mfma(
    const bf16* __restrict__ h, const bf16* __restrict__ Wt2,
    const float* __restrict__ b2, float* __restrict__ out, int M)
{
    constexpr int K = HID, LDB = K + 8;
    __shared__ bf16 Bs[64 * LDB];

    const int tid = threadIdx.x;
    constexpr int CPR = K / 8;
    for (int f = tid; f < 64 * CPR; f += 256) {
        int row = f / CPR;
        int kc  = (f % CPR) * 8;
        *(uint4*)&Bs[row * LDB + kc] = *(const uint4*)(Wt2 + (size_t)row * K + kc);
    }
    __syncthreads();

    const int wv   = tid >> 6;
    const int lane = tid & 63;
    const int l31  = lane & 31;
    const int lhi  = lane >> 5;
    const int blockRow = blockIdx.x * 128;
    const int arow = min(blockRow + wv * 32 + l31, M - 1);

    f32x16 acc[2];
#pragma unroll
    for (int t = 0; t < 2; ++t)
#pragma unroll
        for (int r = 0; r < 16; ++r) acc[t][r] = 0.0f;

#pragma unroll
    for (int ks = 0; ks < K / 16; ++ks) {
        bf16x8 a = *(const bf16x8*)(h + (size_t)arow * K + ks * 16 + lhi * 8);
#pragma unroll
        for (int t = 0; t < 2; ++t) {
            bf16x8 b = *(const bf16x8*)&Bs[(t * 32 + l31) * LDB + ks * 16 + lhi * 8];
            acc[t] = __builtin_amdgcn_mfma_f32_32x32x16_bf16(a, b, acc[t], 0, 0, 0);
        }
    }

    const float bc0 = b2[l31];
    const float bc1 = (l31 < 8) ? b2[32 + l31] : 0.0f;

#pragma unroll
    for (int r = 0; r < 16; ++r) {
        float v0 = acc[0][r] + bc0;
        float v1 = (l31 < 8) ? (acc[1][r] + bc1) : -INFINITY;

        float m = fmaxf(v0, v1);
#pragma unroll
        for (int off = 16; off > 0; off >>= 1)
            m = fmaxf(m, __shfl_xor(m, off, 64));

        float s = __expf(v0 - m) + ((l31 < 8) ? __expf(v1 - m) : 0.0f);
#pragma unroll
        for (int off = 16; off > 0; off >>= 1)
            s += __shfl_xor(s, off, 64);

        float ls = __logf(s);
        int grow = blockRow + wv * 32 + (r & 3) + 8 * (r >> 2) + 4 * lhi;
        if (grow < M) {
            out[(size_t)grow * NCLS + l31] = v0 - m - ls;
            if (l31 < 8)
                out[(size_t)grow * NCLS + 32 + l31] = v1 - m - ls;
        }
    }
}

extern "C" void kernel_launch(void* const* d_in, const int* in_sizes, int n_in,
                              void* d_out, int out_size, void* d_ws, size_t ws_size,
                              hipStream_t stream)
{
    const float* x      = (const float*)d_in[0];
    const float* degree = (const float*)d_in[1];
    const int*   ends   = (const int*)  d_in[2];
    const float* att    = (const float*)d_in[3];
    const float* W0     = (const float*)d_in[4];
    const float* b0     = (const float*)d_in[5];
    const float* W1     = (const float*)d_in[6];
    const float* b1     = (const float*)d_in[7];
    const float* W2     = (const float*)d_in[8];
    const float* b2     = (const float*)d_in[9];
    float* out = (float*)d_out;

    bf16* hb0 = (bf16*)d_ws;                               // [NNODES, HID] bf16
    bf16* hb1 = hb0 + (size_t)NNODES * HID;                // [NNODES, HID] bf16
    unsigned char* hf8 = (unsigned char*)(hb1 + (size_t)NNODES * HID);  // [NNODES,128] fp8 (rsqrt-scaled)
    bf16* Wt0 = (bf16*)(hf8 + (size_t)NNODES * HID);       // [128, 256]
    bf16* Wt1 = Wt0 + 128 * 256;                           // [128, 128]
    bf16* Wt2 = Wt1 + 128 * 128;                           // [64, 128]

    const int prepN = 128 * 256 + 128 * 128 + 64 * 128;
    prep_w<<<(prepN + 255) / 256, 256, 0, stream>>>(W0, W1, W2, Wt0, Wt1, Wt2);

    const int gGemm = (NNODES + 127) / 128;
    const int gAgg  = (NNODES + 7) / 8;        // 2 nodes/wave, 4 waves/block

    // layer 0
    gemm_nodes<NFEAT, false><<<gGemm, 256, 0, stream>>>(x, Wt0, b0, degree, hf8, NNODES);
    agg_relu_fp8<<<gAgg, 256, 0, stream>>>(hf8, hb1, ends, degree, att);
    // layer 1
    gemm_nodes<HID, true><<<gGemm, 256, 0, stream>>>(hb1, Wt1, b1, degree, hf8, NNODES);
    agg_relu_fp8<<<gAgg, 256, 0, stream>>>(
        hf8, hb0, ends + (size_t)KHOP * NNODES * RWSAMP, degree, att + KP1);
    // head
    head_mfma<<<gGemm, 256, 0, stream>>>(hb0, Wt2, b2, out, NNODES);
}